// Round 5
// baseline (198.975 us; speedup 1.0000x reference)
//
#include <hip/hip_runtime.h>
#include <cstdint>
#include <cstddef>

#define DIM 128
#define BM 128
#define NB1 128          // blocks for bucket hist/scatter
#define RBITS 14         // degree-histogram range bits
#define RSIZE (1 << RBITS)
#define NB2 32           // blocks per degree range

typedef __attribute__((ext_vector_type(8))) short bf16x8;
typedef __attribute__((ext_vector_type(16))) float f32x16;

__device__ inline unsigned short f2b(float x) {  // fp32 -> bf16 RNE
    unsigned int u = __float_as_uint(x);
    unsigned int r = (u + 0x7fffu + ((u >> 16) & 1u)) >> 16;
    return (unsigned short)r;
}
__device__ inline float blo(unsigned int u) { return __uint_as_float(u << 16); }
__device__ inline float bhi(unsigned int u) { return __uint_as_float(u & 0xffff0000u); }

// ---- K1: per-block LDS-private coarse histogram of col>>bshift (no atomics)
__global__ __launch_bounds__(256) void bucket_hist_kernel(
    const int* __restrict__ col, int* __restrict__ counts,
    int E, int chunk, int nbuk, int bshift)
{
    extern __shared__ int hs[];
    for (int i = threadIdx.x; i < nbuk; i += 256) hs[i] = 0;
    __syncthreads();
    int e0 = blockIdx.x * chunk;
    int e1 = min(E, e0 + chunk);
    for (int e = e0 + threadIdx.x; e < e1; e += 256)
        atomicAdd(&hs[col[e] >> bshift], 1);
    __syncthreads();
    int* out = counts + (size_t)blockIdx.x * nbuk;
    for (int i = threadIdx.x; i < nbuk; i += 256) out[i] = hs[i];
}

// ---- K2: bucket starts + per-(block,bucket) bases (counts rewritten in place)
__global__ __launch_bounds__(1024) void csr_scan_kernel(
    int* __restrict__ counts, int* __restrict__ bstart, int nbuk, int nb1, int E)
{
    __shared__ int buf[1024];
    int t = threadIdx.x;
    int tot = 0;
    if (t < nbuk)
        for (int b = 0; b < nb1; ++b) tot += counts[(size_t)b * nbuk + t];
    buf[t] = tot;
    __syncthreads();
    for (int s = 1; s < 1024; s <<= 1) {
        int x = (t >= s) ? buf[t - s] : 0;
        __syncthreads();
        buf[t] += x;
        __syncthreads();
    }
    int excl = buf[t] - tot;
    if (t < nbuk) {
        bstart[t] = excl;
        if (t == nbuk - 1) bstart[nbuk] = excl + tot;
        int run = excl;
        for (int b = 0; b < nb1; ++b) {
            int c = counts[(size_t)b * nbuk + t];
            counts[(size_t)b * nbuk + t] = run;
            run += c;
        }
    }
}

// ---- K3: scatter edges into coarse-bucket regions (LDS cursors only)
__global__ __launch_bounds__(256) void bucket_scatter_kernel(
    const int* __restrict__ row, const int* __restrict__ col,
    const int* __restrict__ bases, unsigned int* __restrict__ tmp,
    int E, int chunk, int nbuk, int bshift)
{
    extern __shared__ int cur[];
    const int* mybase = bases + (size_t)blockIdx.x * nbuk;
    for (int i = threadIdx.x; i < nbuk; i += 256) cur[i] = mybase[i];
    __syncthreads();
    int e0 = blockIdx.x * chunk;
    int e1 = min(E, e0 + chunk);
    int rsh = 32 - bshift;
    unsigned int smask = (1u << bshift) - 1u;
    for (int e = e0 + threadIdx.x; e < e1; e += 256) {
        int c = col[e];
        int pos = atomicAdd(&cur[c >> bshift], 1);
        tmp[pos] = (((unsigned int)c & smask) << rsh) | (unsigned int)row[e];
    }
}

// ---- K4: group each bucket by exact col; emit off[] and csr_row[]
__global__ __launch_bounds__(256) void bucket_group_kernel(
    const unsigned int* __restrict__ tmp, const int* __restrict__ bstart,
    int* __restrict__ off, int* __restrict__ csr, int n, int E, int bshift)
{
    __shared__ int subh[4096];
    const int b = blockIdx.x;
    const int tid = threadIdx.x;
    const int subb = 1 << bshift;
    const int rsh = 32 - bshift;
    const unsigned int rmask = (1u << rsh) - 1u;
    int beg = bstart[b], end = bstart[b + 1];

    for (int i = tid; i < subb; i += 256) subh[i] = 0;
    __syncthreads();
    for (int i = beg + tid; i < end; i += 256)
        atomicAdd(&subh[tmp[i] >> rsh], 1);
    __syncthreads();
    // exclusive scan of subb counters
    if (subb <= 64) {
        if (tid < 64) {
            int v = (tid < subb) ? subh[tid] : 0;
            int x = v;
            for (int d = 1; d < 64; d <<= 1) {
                int y = __shfl_up(x, (unsigned)d, 64);
                if (tid >= d) x += y;
            }
            if (tid < subb) subh[tid] = x - v;
        }
    } else {
        if (tid == 0) {
            int run = 0;
            for (int i = 0; i < subb; ++i) { int c = subh[i]; subh[i] = run; run += c; }
        }
    }
    __syncthreads();
    int c0 = b << bshift;
    for (int i = tid; i < subb; i += 256) {
        int c = c0 + i;
        if (c < n) off[c] = beg + subh[i];
    }
    if (b == gridDim.x - 1 && tid == 0) off[n] = E;
    __syncthreads();
    for (int i = beg + tid; i < end; i += 256) {
        unsigned int v = tmp[i];
        int rank = atomicAdd(&subh[v >> rsh], 1);
        csr[beg + rank] = (int)(v & rmask);
    }
}

// ---- D1: range-split LDS-private exact out-degree histogram (no atomics) ----
__global__ __launch_bounds__(256) void deg_hist_kernel(
    const int* __restrict__ row, int* __restrict__ gcounts, int E)
{
    __shared__ int hs[RSIZE];   // 64 KB
    int r = blockIdx.x / NB2, bi = blockIdx.x % NB2;
    for (int i = threadIdx.x; i < RSIZE; i += 256) hs[i] = 0;
    __syncthreads();
    int chunk = (E + NB2 - 1) / NB2;
    int e0 = bi * chunk, e1 = min(E, e0 + chunk);
    for (int e = e0 + threadIdx.x; e < e1; e += 256) {
        int rv = row[e];
        if ((rv >> RBITS) == r) atomicAdd(&hs[rv & (RSIZE - 1)], 1);
    }
    __syncthreads();
    int* out = gcounts + (size_t)blockIdx.x * RSIZE;
    for (int i = threadIdx.x; i < RSIZE; i += 256) out[i] = hs[i];
}

__global__ __launch_bounds__(256) void dinv_kernel(
    const int* __restrict__ gcounts, float* __restrict__ dinv, int n)
{
    int i = blockIdx.x * 256 + threadIdx.x;
    if (i >= n) return;
    int r = i >> RBITS, bl = i & (RSIZE - 1);
    int s = 0;
    for (int bi = 0; bi < NB2; ++bi)
        s += gcounts[(size_t)(r * NB2 + bi) * RSIZE + bl];
    dinv[i] = rsqrtf((float)max(s, 1));
}

// ---------------- transform: bf16 MFMA GEMM --------------------------------
__global__ __launch_bounds__(256) void transform_kernel(
    const float* __restrict__ hin, const float* __restrict__ Wt,
    const float* __restrict__ bt, const float* __restrict__ Wg,
    const float* __restrict__ bg, const float* __restrict__ dinv,
    unsigned short* __restrict__ h1b, float* __restrict__ aout, int n)
{
    __shared__ __align__(16) unsigned short h_s[BM * DIM];   // 32 KB
    __shared__ __align__(16) unsigned short w_s[DIM * DIM];  // 32 KB
    __shared__ float p_s[BM];

    const int tid = threadIdx.x;
    const int node0 = blockIdx.x * BM;
    const int lane = tid & 63;
    const int wv = tid >> 6;

#pragma unroll
    for (int it = 0; it < 16; ++it) {
        int g = it * 256 + tid;
        int r = g >> 5;
        int c4 = g & 31;
        int src = node0 + r;
        if (src >= n) src = n - 1;
        float4 hv = *(const float4*)(hin + (size_t)src * DIM + c4 * 4);
        float4 wvv = *(const float4*)(Wt + (size_t)r * DIM + c4 * 4);
        int chunk = (c4 >> 1) ^ (r & 15);
        int base = r * DIM + chunk * 8 + (c4 & 1) * 4;
        h_s[base + 0] = f2b(hv.x); h_s[base + 1] = f2b(hv.y);
        h_s[base + 2] = f2b(hv.z); h_s[base + 3] = f2b(hv.w);
        w_s[base + 0] = f2b(wvv.x); w_s[base + 1] = f2b(wvv.y);
        w_s[base + 2] = f2b(wvv.z); w_s[base + 3] = f2b(wvv.w);
    }
    __syncthreads();

    f32x16 acc[4] = {};
    const int l31 = lane & 31;
    const int asel = lane >> 5;
    const int swz = l31 & 15;
    const unsigned short* ha = h_s + (wv * 32 + l31) * DIM;
#pragma unroll
    for (int ks = 0; ks < 8; ++ks) {
        int ch = ((ks * 2 + asel) ^ swz) * 8;
        bf16x8 av = *(const bf16x8*)(ha + ch);
#pragma unroll
        for (int cf = 0; cf < 4; ++cf) {
            bf16x8 bv = *(const bf16x8*)(w_s + (cf * 32 + l31) * DIM + ch);
            acc[cf] = __builtin_amdgcn_mfma_f32_32x32x16_bf16(av, bv, acc[cf], 0, 0, 0);
        }
    }
    __syncthreads();

    float btc[4], wgc[4];
#pragma unroll
    for (int cf = 0; cf < 4; ++cf) {
        btc[cf] = bt[cf * 32 + l31];
        wgc[cf] = Wg[cf * 32 + l31];
    }
    float p[16];
#pragma unroll
    for (int q = 0; q < 16; ++q) p[q] = 0.0f;
#pragma unroll
    for (int cf = 0; cf < 4; ++cf) {
#pragma unroll
        for (int q = 0; q < 16; ++q) {
            float v = acc[cf][q] + btc[cf];
            p[q] = fmaf(v, wgc[cf], p[q]);
            int row = (q & 3) + 8 * (q >> 2) + 4 * asel;
            h_s[(wv * 32 + row) * DIM + cf * 32 + l31] = f2b(v);
        }
    }
#pragma unroll
    for (int m = 1; m < 32; m <<= 1) {
#pragma unroll
        for (int q = 0; q < 16; ++q) p[q] += __shfl_xor(p[q], m, 64);
    }
    if (l31 == 0) {
#pragma unroll
        for (int q = 0; q < 16; ++q) {
            int row = (q & 3) + 8 * (q >> 2) + 4 * asel;
            p_s[wv * 32 + row] = p[q];
        }
    }
    __syncthreads();

#pragma unroll
    for (int it = 0; it < 8; ++it) {
        int g = it * 256 + tid;
        int r = g >> 4;
        int c = g & 15;
        int4 v = *(const int4*)(h_s + r * DIM + c * 8);
        int dst = node0 + r;
        if (dst < n) *(int4*)(h1b + (size_t)dst * DIM + c * 8) = v;
    }

    if (tid < BM) {
        int node = node0 + tid;
        if (node < n) aout[node] = tanhf(p_s[tid] + bg[0]) * dinv[node];
    }
}

// ---------------- aggregation: out[c] = relu(dinv[c]*sum(a[r]*h1[r]) + h1[c])
__global__ __launch_bounds__(256) void agg_kernel(
    const int* __restrict__ off, const int* __restrict__ csr_row,
    const float* __restrict__ a, const float* __restrict__ dinv,
    const unsigned short* __restrict__ h1b, float* __restrict__ out, int n)
{
    int node = blockIdx.x * 4 + (threadIdx.x >> 6);
    if (node >= n) return;
    int lane = threadIdx.x & 63;
    int beg = off[node], end = off[node + 1];
    const unsigned int* hb = (const unsigned int*)h1b;
    float s0x = 0.f, s0y = 0.f, s1x = 0.f, s1y = 0.f;
    float s2x = 0.f, s2y = 0.f, s3x = 0.f, s3y = 0.f;
    int s = beg;
    for (; s + 4 <= end; s += 4) {
        int r0 = csr_row[s], r1 = csr_row[s + 1], r2 = csr_row[s + 2], r3 = csr_row[s + 3];
        float a0 = a[r0], a1 = a[r1], a2 = a[r2], a3 = a[r3];
        unsigned int u0 = hb[(size_t)r0 * 64 + lane];
        unsigned int u1 = hb[(size_t)r1 * 64 + lane];
        unsigned int u2 = hb[(size_t)r2 * 64 + lane];
        unsigned int u3 = hb[(size_t)r3 * 64 + lane];
        s0x = fmaf(a0, blo(u0), s0x); s0y = fmaf(a0, bhi(u0), s0y);
        s1x = fmaf(a1, blo(u1), s1x); s1y = fmaf(a1, bhi(u1), s1y);
        s2x = fmaf(a2, blo(u2), s2x); s2y = fmaf(a2, bhi(u2), s2y);
        s3x = fmaf(a3, blo(u3), s3x); s3y = fmaf(a3, bhi(u3), s3y);
    }
    for (; s < end; ++s) {
        int r0 = csr_row[s];
        float a0 = a[r0];
        unsigned int u0 = hb[(size_t)r0 * 64 + lane];
        s0x = fmaf(a0, blo(u0), s0x); s0y = fmaf(a0, bhi(u0), s0y);
    }
    float dv = dinv[node];
    unsigned int ur = hb[(size_t)node * 64 + lane];
    float2 o;
    o.x = fmaxf(fmaf(dv, s0x + s1x + s2x + s3x, blo(ur)), 0.0f);
    o.y = fmaxf(fmaf(dv, s0y + s1y + s2y + s3y, bhi(ur)), 0.0f);
    ((float2*)out)[(size_t)node * 64 + lane] = o;
}

extern "C" void kernel_launch(void* const* d_in, const int* in_sizes, int n_in,
                              void* d_out, int out_size, void* d_ws, size_t ws_size,
                              hipStream_t stream) {
    const float* x    = (const float*)d_in[0];
    const int*   edge = (const int*)d_in[1];
    const float* Wt   = (const float*)d_in[2];
    const float* bt   = (const float*)d_in[3];
    const float* Wg   = (const float*)d_in[4];
    const float* bg   = (const float*)d_in[5];
    float* out = (float*)d_out;

    const int n = in_sizes[0] / DIM;      // 50000
    const int E = in_sizes[1] / 2;        // 600000
    const int* row = edge;
    const int* col = edge + E;

    int bshift = 6;
    while (((n + (1 << bshift) - 1) >> bshift) > 1024) ++bshift;
    const int nbuk = (n + (1 << bshift) - 1) >> bshift;
    const int nr = (n + RSIZE - 1) >> RBITS;

    // ---- byte-carved workspace ----
    char* base = (char*)d_ws;
    size_t o = 0;
    auto carve = [&](size_t bytes) -> void* {
        void* p = base + o;
        o += (bytes + 255) & ~(size_t)255;
        return p;
    };
    unsigned short* h1b  = (unsigned short*)carve((size_t)n * DIM * 2);
    float* dinv          = (float*)carve((size_t)n * 4);
    float* a             = (float*)carve((size_t)n * 4);
    int*   off           = (int*)carve((size_t)(n + 1) * 4);
    int*   csr           = (int*)carve((size_t)E * 4);
    unsigned int* tmp    = (unsigned int*)carve((size_t)E * 4);
    int*   counts        = (int*)carve((size_t)NB1 * nbuk * 4);
    int*   bstart        = (int*)carve((size_t)(nbuk + 1) * 4);
    int*   gcounts       = (int*)carve((size_t)nr * NB2 * RSIZE * 4);

    const int chunk1 = (E + NB1 - 1) / NB1;
    const size_t ldsb = (size_t)nbuk * 4;

    // ---- degree -> dinv (atomic-free) ----
    deg_hist_kernel<<<nr * NB2, 256, 0, stream>>>(row, gcounts, E);
    dinv_kernel<<<(n + 255) / 256, 256, 0, stream>>>(gcounts, dinv, n);

    // ---- CSR build (atomic-free at global scope) ----
    bucket_hist_kernel<<<NB1, 256, ldsb, stream>>>(col, counts, E, chunk1, nbuk, bshift);
    csr_scan_kernel<<<1, 1024, 0, stream>>>(counts, bstart, nbuk, NB1, E);
    bucket_scatter_kernel<<<NB1, 256, ldsb, stream>>>(row, col, counts, tmp, E, chunk1, nbuk, bshift);
    bucket_group_kernel<<<nbuk, 256, 0, stream>>>(tmp, bstart, off, csr, n, E, bshift);

    // ---- two FA layers ----
    const int gt = (n + BM - 1) / BM;
    for (int l = 0; l < 2; ++l) {
        const float* hin = (l == 0) ? x : out;
        const float* Wtl = Wt + (size_t)l * DIM * DIM;
        const float* btl = bt + (size_t)l * DIM;
        const float* Wgl = Wg + (size_t)l * DIM;
        const float* bgl = bg + l;

        transform_kernel<<<gt, 256, 0, stream>>>(
            hin, Wtl, btl, Wgl, bgl, dinv, h1b, a, n);
        agg_kernel<<<(n + 3) / 4, 256, 0, stream>>>(off, csr, a, dinv, h1b, out, n);
    }
}

// Round 6
// 158.418 us; speedup vs baseline: 1.2560x; 1.2560x over previous
//
#include <hip/hip_runtime.h>
#include <cstdint>
#include <cstddef>

#define DIM 128
#define BM 128
#define NB1 128          // blocks for bucket hist/scatter (fixed; col_scan assumes 128)
#define RBITS 14         // degree-histogram range bits
#define RSIZE (1 << RBITS)
#define NB2 32           // blocks per degree range

typedef __attribute__((ext_vector_type(8))) short bf16x8;
typedef __attribute__((ext_vector_type(16))) float f32x16;

__device__ inline unsigned short f2b(float x) {  // fp32 -> bf16 RNE
    unsigned int u = __float_as_uint(x);
    unsigned int r = (u + 0x7fffu + ((u >> 16) & 1u)) >> 16;
    return (unsigned short)r;
}
__device__ inline float blo(unsigned int u) { return __uint_as_float(u << 16); }
__device__ inline float bhi(unsigned int u) { return __uint_as_float(u & 0xffff0000u); }

// ---- K1: per-block LDS-private coarse histogram of col>>bshift (no atomics)
__global__ __launch_bounds__(256) void bucket_hist_kernel(
    const int* __restrict__ col, int* __restrict__ counts,
    int E, int chunk, int nbuk, int bshift)
{
    extern __shared__ int hs[];
    for (int i = threadIdx.x; i < nbuk; i += 256) hs[i] = 0;
    __syncthreads();
    int e0 = blockIdx.x * chunk;
    int e1 = min(E, e0 + chunk);
    for (int e = e0 + threadIdx.x; e < e1; e += 256)
        atomicAdd(&hs[col[e] >> bshift], 1);
    __syncthreads();
    int* out = counts + (size_t)blockIdx.x * nbuk;
    for (int i = threadIdx.x; i < nbuk; i += 256) out[i] = hs[i];
}

// ---- K2a: per-bucket column scan over the NB1=128 block counts -------------
// one wave per bucket; lane owns blocks lane*2, lane*2+1. Rewrites counts[]
// into per-(block,bucket) exclusive bases (without bstart offset); emits
// column totals.
__global__ __launch_bounds__(256) void col_scan_kernel(
    int* __restrict__ counts, int* __restrict__ tot, int nbuk)
{
    int w = threadIdx.x >> 6;
    int lane = threadIdx.x & 63;
    int t = blockIdx.x * 4 + w;
    if (t >= nbuk) return;
    int c0 = counts[(size_t)(lane * 2) * nbuk + t];
    int c1 = counts[(size_t)(lane * 2 + 1) * nbuk + t];
    int s = c0 + c1;
    int x = s;
#pragma unroll
    for (int d = 1; d < 64; d <<= 1) {
        int y = __shfl_up(x, (unsigned)d, 64);
        if (lane >= d) x += y;
    }
    int excl = x - s;
    counts[(size_t)(lane * 2) * nbuk + t] = excl;
    counts[(size_t)(lane * 2 + 1) * nbuk + t] = excl + c0;
    if (lane == 63) tot[t] = x;
}

// ---- K2b: exclusive scan of bucket totals -> bstart ------------------------
__global__ __launch_bounds__(1024) void bstart_scan_kernel(
    const int* __restrict__ tot, int* __restrict__ bstart, int nbuk, int E)
{
    __shared__ int buf[1024];
    int t = threadIdx.x;
    int v = (t < nbuk) ? tot[t] : 0;
    buf[t] = v;
    __syncthreads();
    for (int s = 1; s < 1024; s <<= 1) {
        int x = (t >= s) ? buf[t - s] : 0;
        __syncthreads();
        buf[t] += x;
        __syncthreads();
    }
    if (t < nbuk) bstart[t] = buf[t] - v;
    if (t == 0) bstart[nbuk] = E;
}

// ---- K3: scatter edges into coarse-bucket regions (LDS cursors only)
__global__ __launch_bounds__(256) void bucket_scatter_kernel(
    const int* __restrict__ row, const int* __restrict__ col,
    const int* __restrict__ bases, const int* __restrict__ bstart,
    unsigned int* __restrict__ tmp,
    int E, int chunk, int nbuk, int bshift)
{
    extern __shared__ int cur[];
    const int* mybase = bases + (size_t)blockIdx.x * nbuk;
    for (int i = threadIdx.x; i < nbuk; i += 256) cur[i] = mybase[i] + bstart[i];
    __syncthreads();
    int e0 = blockIdx.x * chunk;
    int e1 = min(E, e0 + chunk);
    int rsh = 32 - bshift;
    unsigned int smask = (1u << bshift) - 1u;
    for (int e = e0 + threadIdx.x; e < e1; e += 256) {
        int c = col[e];
        int pos = atomicAdd(&cur[c >> bshift], 1);
        tmp[pos] = (((unsigned int)c & smask) << rsh) | (unsigned int)row[e];
    }
}

// ---- K4: group each bucket by exact col; emit off[] and csr_row[]
__global__ __launch_bounds__(256) void bucket_group_kernel(
    const unsigned int* __restrict__ tmp, const int* __restrict__ bstart,
    int* __restrict__ off, int* __restrict__ csr, int n, int E, int bshift)
{
    __shared__ int subh[4096];
    const int b = blockIdx.x;
    const int tid = threadIdx.x;
    const int subb = 1 << bshift;
    const int rsh = 32 - bshift;
    const unsigned int rmask = (1u << rsh) - 1u;
    int beg = bstart[b], end = bstart[b + 1];

    for (int i = tid; i < subb; i += 256) subh[i] = 0;
    __syncthreads();
    for (int i = beg + tid; i < end; i += 256)
        atomicAdd(&subh[tmp[i] >> rsh], 1);
    __syncthreads();
    if (subb <= 64) {
        if (tid < 64) {
            int v = (tid < subb) ? subh[tid] : 0;
            int x = v;
            for (int d = 1; d < 64; d <<= 1) {
                int y = __shfl_up(x, (unsigned)d, 64);
                if (tid >= d) x += y;
            }
            if (tid < subb) subh[tid] = x - v;
        }
    } else {
        if (tid == 0) {
            int run = 0;
            for (int i = 0; i < subb; ++i) { int c = subh[i]; subh[i] = run; run += c; }
        }
    }
    __syncthreads();
    int c0 = b << bshift;
    for (int i = tid; i < subb; i += 256) {
        int c = c0 + i;
        if (c < n) off[c] = beg + subh[i];
    }
    if (b == gridDim.x - 1 && tid == 0) off[n] = E;
    __syncthreads();
    for (int i = beg + tid; i < end; i += 256) {
        unsigned int v = tmp[i];
        int rank = atomicAdd(&subh[v >> rsh], 1);
        csr[beg + rank] = (int)(v & rmask);
    }
}

// ---- D1: range-split LDS-private exact out-degree histogram (no atomics) ----
__global__ __launch_bounds__(256) void deg_hist_kernel(
    const int* __restrict__ row, int* __restrict__ gcounts, int E)
{
    __shared__ int hs[RSIZE];   // 64 KB
    int r = blockIdx.x / NB2, bi = blockIdx.x % NB2;
    for (int i = threadIdx.x; i < RSIZE; i += 256) hs[i] = 0;
    __syncthreads();
    int chunk = (E + NB2 - 1) / NB2;
    int e0 = bi * chunk, e1 = min(E, e0 + chunk);
    for (int e = e0 + threadIdx.x; e < e1; e += 256) {
        int rv = row[e];
        if ((rv >> RBITS) == r) atomicAdd(&hs[rv & (RSIZE - 1)], 1);
    }
    __syncthreads();
    int* out = gcounts + (size_t)blockIdx.x * RSIZE;
    for (int i = threadIdx.x; i < RSIZE; i += 256) out[i] = hs[i];
}

__global__ __launch_bounds__(256) void dinv_kernel(
    const int* __restrict__ gcounts, float* __restrict__ dinv, int n)
{
    int i = blockIdx.x * 256 + threadIdx.x;
    if (i >= n) return;
    int r = i >> RBITS, bl = i & (RSIZE - 1);
    int s = 0;
    for (int bi = 0; bi < NB2; ++bi)
        s += gcounts[(size_t)(r * NB2 + bi) * RSIZE + bl];
    dinv[i] = rsqrtf((float)max(s, 1));
}

// ---------------- transform: bf16 MFMA GEMM --------------------------------
__global__ __launch_bounds__(256) void transform_kernel(
    const float* __restrict__ hin, const float* __restrict__ Wt,
    const float* __restrict__ bt, const float* __restrict__ Wg,
    const float* __restrict__ bg, const float* __restrict__ dinv,
    unsigned short* __restrict__ h1b, float* __restrict__ aout, int n)
{
    __shared__ __align__(16) unsigned short h_s[BM * DIM];   // 32 KB
    __shared__ __align__(16) unsigned short w_s[DIM * DIM];  // 32 KB
    __shared__ float p_s[BM];

    const int tid = threadIdx.x;
    const int node0 = blockIdx.x * BM;
    const int lane = tid & 63;
    const int wv = tid >> 6;

#pragma unroll
    for (int it = 0; it < 16; ++it) {
        int g = it * 256 + tid;
        int r = g >> 5;
        int c4 = g & 31;
        int src = node0 + r;
        if (src >= n) src = n - 1;
        float4 hv = *(const float4*)(hin + (size_t)src * DIM + c4 * 4);
        float4 wvv = *(const float4*)(Wt + (size_t)r * DIM + c4 * 4);
        int chunk = (c4 >> 1) ^ (r & 15);
        int base = r * DIM + chunk * 8 + (c4 & 1) * 4;
        h_s[base + 0] = f2b(hv.x); h_s[base + 1] = f2b(hv.y);
        h_s[base + 2] = f2b(hv.z); h_s[base + 3] = f2b(hv.w);
        w_s[base + 0] = f2b(wvv.x); w_s[base + 1] = f2b(wvv.y);
        w_s[base + 2] = f2b(wvv.z); w_s[base + 3] = f2b(wvv.w);
    }
    __syncthreads();

    f32x16 acc[4] = {};
    const int l31 = lane & 31;
    const int asel = lane >> 5;
    const int swz = l31 & 15;
    const unsigned short* ha = h_s + (wv * 32 + l31) * DIM;
#pragma unroll
    for (int ks = 0; ks < 8; ++ks) {
        int ch = ((ks * 2 + asel) ^ swz) * 8;
        bf16x8 av = *(const bf16x8*)(ha + ch);
#pragma unroll
        for (int cf = 0; cf < 4; ++cf) {
            bf16x8 bv = *(const bf16x8*)(w_s + (cf * 32 + l31) * DIM + ch);
            acc[cf] = __builtin_amdgcn_mfma_f32_32x32x16_bf16(av, bv, acc[cf], 0, 0, 0);
        }
    }
    __syncthreads();

    float btc[4], wgc[4];
#pragma unroll
    for (int cf = 0; cf < 4; ++cf) {
        btc[cf] = bt[cf * 32 + l31];
        wgc[cf] = Wg[cf * 32 + l31];
    }
    float p[16];
#pragma unroll
    for (int q = 0; q < 16; ++q) p[q] = 0.0f;
#pragma unroll
    for (int cf = 0; cf < 4; ++cf) {
#pragma unroll
        for (int q = 0; q < 16; ++q) {
            float v = acc[cf][q] + btc[cf];
            p[q] = fmaf(v, wgc[cf], p[q]);
            int row = (q & 3) + 8 * (q >> 2) + 4 * asel;
            h_s[(wv * 32 + row) * DIM + cf * 32 + l31] = f2b(v);
        }
    }
#pragma unroll
    for (int m = 1; m < 32; m <<= 1) {
#pragma unroll
        for (int q = 0; q < 16; ++q) p[q] += __shfl_xor(p[q], m, 64);
    }
    if (l31 == 0) {
#pragma unroll
        for (int q = 0; q < 16; ++q) {
            int row = (q & 3) + 8 * (q >> 2) + 4 * asel;
            p_s[wv * 32 + row] = p[q];
        }
    }
    __syncthreads();

#pragma unroll
    for (int it = 0; it < 8; ++it) {
        int g = it * 256 + tid;
        int r = g >> 4;
        int c = g & 15;
        int4 v = *(const int4*)(h_s + r * DIM + c * 8);
        int dst = node0 + r;
        if (dst < n) *(int4*)(h1b + (size_t)dst * DIM + c * 8) = v;
    }

    if (tid < BM) {
        int node = node0 + tid;
        if (node < n) aout[node] = tanhf(p_s[tid] + bg[0]) * dinv[node];
    }
}

// ---------------- aggregation: out[c] = relu(dinv[c]*sum(a[r]*h1[r]) + h1[c])
__global__ __launch_bounds__(256) void agg_kernel(
    const int* __restrict__ off, const int* __restrict__ csr_row,
    const float* __restrict__ a, const float* __restrict__ dinv,
    const unsigned short* __restrict__ h1b, float* __restrict__ out, int n)
{
    int node = blockIdx.x * 4 + (threadIdx.x >> 6);
    if (node >= n) return;
    int lane = threadIdx.x & 63;
    int beg = off[node], end = off[node + 1];
    const unsigned int* hb = (const unsigned int*)h1b;
    float s0x = 0.f, s0y = 0.f, s1x = 0.f, s1y = 0.f;
    float s2x = 0.f, s2y = 0.f, s3x = 0.f, s3y = 0.f;
    int s = beg;
    for (; s + 4 <= end; s += 4) {
        int r0 = csr_row[s], r1 = csr_row[s + 1], r2 = csr_row[s + 2], r3 = csr_row[s + 3];
        float a0 = a[r0], a1 = a[r1], a2 = a[r2], a3 = a[r3];
        unsigned int u0 = hb[(size_t)r0 * 64 + lane];
        unsigned int u1 = hb[(size_t)r1 * 64 + lane];
        unsigned int u2 = hb[(size_t)r2 * 64 + lane];
        unsigned int u3 = hb[(size_t)r3 * 64 + lane];
        s0x = fmaf(a0, blo(u0), s0x); s0y = fmaf(a0, bhi(u0), s0y);
        s1x = fmaf(a1, blo(u1), s1x); s1y = fmaf(a1, bhi(u1), s1y);
        s2x = fmaf(a2, blo(u2), s2x); s2y = fmaf(a2, bhi(u2), s2y);
        s3x = fmaf(a3, blo(u3), s3x); s3y = fmaf(a3, bhi(u3), s3y);
    }
    for (; s < end; ++s) {
        int r0 = csr_row[s];
        float a0 = a[r0];
        unsigned int u0 = hb[(size_t)r0 * 64 + lane];
        s0x = fmaf(a0, blo(u0), s0x); s0y = fmaf(a0, bhi(u0), s0y);
    }
    float dv = dinv[node];
    unsigned int ur = hb[(size_t)node * 64 + lane];
    float2 o;
    o.x = fmaxf(fmaf(dv, s0x + s1x + s2x + s3x, blo(ur)), 0.0f);
    o.y = fmaxf(fmaf(dv, s0y + s1y + s2y + s3y, bhi(ur)), 0.0f);
    ((float2*)out)[(size_t)node * 64 + lane] = o;
}

extern "C" void kernel_launch(void* const* d_in, const int* in_sizes, int n_in,
                              void* d_out, int out_size, void* d_ws, size_t ws_size,
                              hipStream_t stream) {
    const float* x    = (const float*)d_in[0];
    const int*   edge = (const int*)d_in[1];
    const float* Wt   = (const float*)d_in[2];
    const float* bt   = (const float*)d_in[3];
    const float* Wg   = (const float*)d_in[4];
    const float* bg   = (const float*)d_in[5];
    float* out = (float*)d_out;

    const int n = in_sizes[0] / DIM;      // 50000
    const int E = in_sizes[1] / 2;        // 600000
    const int* row = edge;
    const int* col = edge + E;

    int bshift = 6;
    while (((n + (1 << bshift) - 1) >> bshift) > 1024) ++bshift;
    const int nbuk = (n + (1 << bshift) - 1) >> bshift;
    const int nr = (n + RSIZE - 1) >> RBITS;

    // ---- byte-carved workspace ----
    char* base = (char*)d_ws;
    size_t o = 0;
    auto carve = [&](size_t bytes) -> void* {
        void* p = base + o;
        o += (bytes + 255) & ~(size_t)255;
        return p;
    };
    unsigned short* h1b  = (unsigned short*)carve((size_t)n * DIM * 2);
    float* dinv          = (float*)carve((size_t)n * 4);
    float* a             = (float*)carve((size_t)n * 4);
    int*   off           = (int*)carve((size_t)(n + 1) * 4);
    int*   csr           = (int*)carve((size_t)E * 4);
    unsigned int* tmp    = (unsigned int*)carve((size_t)E * 4);
    int*   counts        = (int*)carve((size_t)NB1 * nbuk * 4);
    int*   bstart        = (int*)carve((size_t)(nbuk + 1) * 4);
    int*   tot           = (int*)carve((size_t)nbuk * 4);
    int*   gcounts       = (int*)carve((size_t)nr * NB2 * RSIZE * 4);

    const int chunk1 = (E + NB1 - 1) / NB1;
    const size_t ldsb = (size_t)nbuk * 4;

    // ---- degree -> dinv (atomic-free) ----
    deg_hist_kernel<<<nr * NB2, 256, 0, stream>>>(row, gcounts, E);
    dinv_kernel<<<(n + 255) / 256, 256, 0, stream>>>(gcounts, dinv, n);

    // ---- CSR build (atomic-free at global scope) ----
    bucket_hist_kernel<<<NB1, 256, ldsb, stream>>>(col, counts, E, chunk1, nbuk, bshift);
    col_scan_kernel<<<(nbuk + 3) / 4, 256, 0, stream>>>(counts, tot, nbuk);
    bstart_scan_kernel<<<1, 1024, 0, stream>>>(tot, bstart, nbuk, E);
    bucket_scatter_kernel<<<NB1, 256, ldsb, stream>>>(row, col, counts, bstart, tmp, E, chunk1, nbuk, bshift);
    bucket_group_kernel<<<nbuk, 256, 0, stream>>>(tmp, bstart, off, csr, n, E, bshift);

    // ---- two FA layers ----
    const int gt = (n + BM - 1) / BM;
    for (int l = 0; l < 2; ++l) {
        const float* hin = (l == 0) ? x : out;
        const float* Wtl = Wt + (size_t)l * DIM * DIM;
        const float* btl = bt + (size_t)l * DIM;
        const float* Wgl = Wg + (size_t)l * DIM;
        const float* bgl = bg + l;

        transform_kernel<<<gt, 256, 0, stream>>>(
            hin, Wtl, btl, Wgl, bgl, dinv, h1b, a, n);
        agg_kernel<<<(n + 3) / 4, 256, 0, stream>>>(off, csr, a, dinv, h1b, out, n);
    }
}

// Round 7
// 149.648 us; speedup vs baseline: 1.3296x; 1.0586x over previous
//
#include <hip/hip_runtime.h>
#include <cstdint>
#include <cstddef>

#define DIM 128
#define BM 128
#define NB1 128          // blocks for bucket hist/scatter
#define RBITS 14         // degree-histogram range bits
#define RSIZE (1 << RBITS)
#define NB2 32           // blocks per degree range

typedef __attribute__((ext_vector_type(8))) short bf16x8;
typedef __attribute__((ext_vector_type(16))) float f32x16;

__device__ inline unsigned short f2b(float x) {  // fp32 -> bf16 RNE
    unsigned int u = __float_as_uint(x);
    unsigned int r = (u + 0x7fffu + ((u >> 16) & 1u)) >> 16;
    return (unsigned short)r;
}
__device__ inline float blo(unsigned int u) { return __uint_as_float(u << 16); }
__device__ inline float bhi(unsigned int u) { return __uint_as_float(u & 0xffff0000u); }

// ---- K_A: fused histograms (deg-by-row ranges + coarse col buckets) --------
// blocks [0, ndeg): out-degree range histograms (64KB LDS each)
// blocks [ndeg, ndeg+NB1): coarse col>>bshift histogram per E/NB1 chunk
__global__ __launch_bounds__(256) void hists_kernel(
    const int* __restrict__ row, const int* __restrict__ col,
    int* __restrict__ gcounts, int* __restrict__ counts,
    int E, int ndeg, int nbuk, int bshift)
{
    __shared__ int hs[RSIZE];   // 64 KB
    int b = blockIdx.x;
    if (b < ndeg) {
        int r = b / NB2, bi = b % NB2;
        for (int i = threadIdx.x; i < RSIZE; i += 256) hs[i] = 0;
        __syncthreads();
        int chunk = (E + NB2 - 1) / NB2;
        int e0 = bi * chunk, e1 = min(E, e0 + chunk);
        for (int e = e0 + threadIdx.x; e < e1; e += 256) {
            int rv = row[e];
            if ((rv >> RBITS) == r) atomicAdd(&hs[rv & (RSIZE - 1)], 1);
        }
        __syncthreads();
        int* outp = gcounts + (size_t)b * RSIZE;
        for (int i = threadIdx.x; i < RSIZE; i += 256) outp[i] = hs[i];
    } else {
        int hb = b - ndeg;
        for (int i = threadIdx.x; i < nbuk; i += 256) hs[i] = 0;
        __syncthreads();
        int chunk = (E + NB1 - 1) / NB1;
        int e0 = hb * chunk, e1 = min(E, e0 + chunk);
        for (int e = e0 + threadIdx.x; e < e1; e += 256)
            atomicAdd(&hs[col[e] >> bshift], 1);
        __syncthreads();
        int* outp = counts + (size_t)hb * nbuk;
        for (int i = threadIdx.x; i < nbuk; i += 256) outp[i] = hs[i];
    }
}

// ---- K_B: fused {per-bucket column scan of NB1 block counts} + {dinv} ------
__global__ __launch_bounds__(256) void scan_dinv_kernel(
    int* __restrict__ counts, int* __restrict__ tot,
    const int* __restrict__ gcounts, float* __restrict__ dinv,
    int nbuk, int n, int nscan)
{
    int b = blockIdx.x;
    if (b < nscan) {
        int w = threadIdx.x >> 6;
        int lane = threadIdx.x & 63;
        int t = b * 4 + w;
        if (t >= nbuk) return;
        int c0 = counts[(size_t)(lane * 2) * nbuk + t];
        int c1 = counts[(size_t)(lane * 2 + 1) * nbuk + t];
        int s = c0 + c1;
        int x = s;
#pragma unroll
        for (int d = 1; d < 64; d <<= 1) {
            int y = __shfl_up(x, (unsigned)d, 64);
            if (lane >= d) x += y;
        }
        int excl = x - s;
        counts[(size_t)(lane * 2) * nbuk + t] = excl;
        counts[(size_t)(lane * 2 + 1) * nbuk + t] = excl + c0;
        if (lane == 63) tot[t] = x;
    } else {
        int i = (b - nscan) * 256 + threadIdx.x;
        if (i >= n) return;
        int r = i >> RBITS, bl = i & (RSIZE - 1);
        int s = 0;
        for (int bi = 0; bi < NB2; ++bi)
            s += gcounts[(size_t)(r * NB2 + bi) * RSIZE + bl];
        dinv[i] = rsqrtf((float)max(s, 1));
    }
}

// ---- K_C: scatter with inline bstart prefix (block 0 publishes bstart) -----
__global__ __launch_bounds__(256) void scatter_kernel(
    const int* __restrict__ row, const int* __restrict__ col,
    const int* __restrict__ bases, const int* __restrict__ tot,
    unsigned int* __restrict__ tmp, int* __restrict__ bstart,
    int E, int nbuk, int bshift)
{
    __shared__ int scanbuf[256];
    __shared__ int bst[1024];
    __shared__ int cur[1024];
    int t = threadIdx.x;
    int v[4];
    int s = 0;
#pragma unroll
    for (int k = 0; k < 4; ++k) {
        int idx = t * 4 + k;
        v[k] = (idx < nbuk) ? tot[idx] : 0;
        s += v[k];
    }
    scanbuf[t] = s;
    __syncthreads();
    for (int d = 1; d < 256; d <<= 1) {
        int y = (t >= d) ? scanbuf[t - d] : 0;
        __syncthreads();
        scanbuf[t] += y;
        __syncthreads();
    }
    int run = scanbuf[t] - s;
#pragma unroll
    for (int k = 0; k < 4; ++k) {
        int idx = t * 4 + k;
        if (idx < nbuk) bst[idx] = run;
        run += v[k];
    }
    __syncthreads();
    const int* mybase = bases + (size_t)blockIdx.x * nbuk;
    for (int i = t; i < nbuk; i += 256) cur[i] = bst[i] + mybase[i];
    if (blockIdx.x == 0) {
        for (int i = t; i < nbuk; i += 256) bstart[i] = bst[i];
        if (t == 0) bstart[nbuk] = E;
    }
    __syncthreads();
    int chunk = (E + NB1 - 1) / NB1;
    int e0 = blockIdx.x * chunk, e1 = min(E, e0 + chunk);
    int rsh = 32 - bshift;
    unsigned int smask = (1u << bshift) - 1u;
    for (int e = e0 + t; e < e1; e += 256) {
        int c = col[e];
        int pos = atomicAdd(&cur[c >> bshift], 1);
        tmp[pos] = (((unsigned int)c & smask) << rsh) | (unsigned int)row[e];
    }
}

// ---- K_D: group each bucket by exact col; emit off[] and csr_row[] ---------
__global__ __launch_bounds__(256) void bucket_group_kernel(
    const unsigned int* __restrict__ tmp, const int* __restrict__ bstart,
    int* __restrict__ off, int* __restrict__ csr, int n, int E, int bshift)
{
    __shared__ int subh[4096];
    const int b = blockIdx.x;
    const int tid = threadIdx.x;
    const int subb = 1 << bshift;
    const int rsh = 32 - bshift;
    const unsigned int rmask = (1u << rsh) - 1u;
    int beg = bstart[b], end = bstart[b + 1];

    for (int i = tid; i < subb; i += 256) subh[i] = 0;
    __syncthreads();
    for (int i = beg + tid; i < end; i += 256)
        atomicAdd(&subh[tmp[i] >> rsh], 1);
    __syncthreads();
    if (subb <= 64) {
        if (tid < 64) {
            int v = (tid < subb) ? subh[tid] : 0;
            int x = v;
            for (int d = 1; d < 64; d <<= 1) {
                int y = __shfl_up(x, (unsigned)d, 64);
                if (tid >= d) x += y;
            }
            if (tid < subb) subh[tid] = x - v;
        }
    } else {
        if (tid == 0) {
            int run = 0;
            for (int i = 0; i < subb; ++i) { int c = subh[i]; subh[i] = run; run += c; }
        }
    }
    __syncthreads();
    int c0 = b << bshift;
    for (int i = tid; i < subb; i += 256) {
        int c = c0 + i;
        if (c < n) off[c] = beg + subh[i];
    }
    if (b == gridDim.x - 1 && tid == 0) off[n] = E;
    __syncthreads();
    for (int i = beg + tid; i < end; i += 256) {
        unsigned int v = tmp[i];
        int rank = atomicAdd(&subh[v >> rsh], 1);
        csr[beg + rank] = (int)(v & rmask);
    }
}

// ---------------- transform: bf16 MFMA GEMM --------------------------------
template <bool BF16IN>
__global__ __launch_bounds__(256) void transform_kernel(
    const void* __restrict__ hin_v, const float* __restrict__ Wt,
    const float* __restrict__ bt, const float* __restrict__ Wg,
    const float* __restrict__ bg, const float* __restrict__ dinv,
    unsigned short* __restrict__ h1b, float* __restrict__ aout, int n)
{
    __shared__ __align__(16) unsigned short h_s[BM * DIM];   // 32 KB
    __shared__ __align__(16) unsigned short w_s[DIM * DIM];  // 32 KB
    __shared__ float p_s[BM];

    const int tid = threadIdx.x;
    const int node0 = blockIdx.x * BM;
    const int lane = tid & 63;
    const int wv = tid >> 6;

#pragma unroll
    for (int it = 0; it < 16; ++it) {
        int g = it * 256 + tid;
        int r = g >> 5;
        int c4 = g & 31;
        int src = node0 + r;
        if (src >= n) src = n - 1;
        int chunk = (c4 >> 1) ^ (r & 15);
        int base = r * DIM + chunk * 8 + (c4 & 1) * 4;
        if constexpr (BF16IN) {
            const unsigned short* hin = (const unsigned short*)hin_v;
            ushort4 hv = *(const ushort4*)(hin + (size_t)src * DIM + c4 * 4);
            h_s[base + 0] = hv.x; h_s[base + 1] = hv.y;
            h_s[base + 2] = hv.z; h_s[base + 3] = hv.w;
        } else {
            const float* hin = (const float*)hin_v;
            float4 hv = *(const float4*)(hin + (size_t)src * DIM + c4 * 4);
            h_s[base + 0] = f2b(hv.x); h_s[base + 1] = f2b(hv.y);
            h_s[base + 2] = f2b(hv.z); h_s[base + 3] = f2b(hv.w);
        }
        float4 wvv = *(const float4*)(Wt + (size_t)r * DIM + c4 * 4);
        w_s[base + 0] = f2b(wvv.x); w_s[base + 1] = f2b(wvv.y);
        w_s[base + 2] = f2b(wvv.z); w_s[base + 3] = f2b(wvv.w);
    }
    __syncthreads();

    f32x16 acc[4] = {};
    const int l31 = lane & 31;
    const int asel = lane >> 5;
    const int swz = l31 & 15;
    const unsigned short* ha = h_s + (wv * 32 + l31) * DIM;
#pragma unroll
    for (int ks = 0; ks < 8; ++ks) {
        int ch = ((ks * 2 + asel) ^ swz) * 8;
        bf16x8 av = *(const bf16x8*)(ha + ch);
#pragma unroll
        for (int cf = 0; cf < 4; ++cf) {
            bf16x8 bv = *(const bf16x8*)(w_s + (cf * 32 + l31) * DIM + ch);
            acc[cf] = __builtin_amdgcn_mfma_f32_32x32x16_bf16(av, bv, acc[cf], 0, 0, 0);
        }
    }
    __syncthreads();

    float btc[4], wgc[4];
#pragma unroll
    for (int cf = 0; cf < 4; ++cf) {
        btc[cf] = bt[cf * 32 + l31];
        wgc[cf] = Wg[cf * 32 + l31];
    }
    float p[16];
#pragma unroll
    for (int q = 0; q < 16; ++q) p[q] = 0.0f;
#pragma unroll
    for (int cf = 0; cf < 4; ++cf) {
#pragma unroll
        for (int q = 0; q < 16; ++q) {
            float v = acc[cf][q] + btc[cf];
            p[q] = fmaf(v, wgc[cf], p[q]);
            int row = (q & 3) + 8 * (q >> 2) + 4 * asel;
            h_s[(wv * 32 + row) * DIM + cf * 32 + l31] = f2b(v);
        }
    }
#pragma unroll
    for (int m = 1; m < 32; m <<= 1) {
#pragma unroll
        for (int q = 0; q < 16; ++q) p[q] += __shfl_xor(p[q], m, 64);
    }
    if (l31 == 0) {
#pragma unroll
        for (int q = 0; q < 16; ++q) {
            int row = (q & 3) + 8 * (q >> 2) + 4 * asel;
            p_s[wv * 32 + row] = p[q];
        }
    }
    __syncthreads();

#pragma unroll
    for (int it = 0; it < 8; ++it) {
        int g = it * 256 + tid;
        int r = g >> 4;
        int c = g & 15;
        int4 v = *(const int4*)(h_s + r * DIM + c * 8);
        int dst = node0 + r;
        if (dst < n) *(int4*)(h1b + (size_t)dst * DIM + c * 8) = v;
    }

    if (tid < BM) {
        int node = node0 + tid;
        if (node < n) aout[node] = tanhf(p_s[tid] + bg[0]) * dinv[node];
    }
}

// ---------------- aggregation: out[c] = relu(dinv[c]*sum(a[r]*h1[r]) + h1[c])
template <bool BF16OUT>
__global__ __launch_bounds__(256) void agg_kernel(
    const int* __restrict__ off, const int* __restrict__ csr_row,
    const float* __restrict__ a, const float* __restrict__ dinv,
    const unsigned short* __restrict__ h1b, void* __restrict__ out_v, int n)
{
    int node = blockIdx.x * 4 + (threadIdx.x >> 6);
    if (node >= n) return;
    int lane = threadIdx.x & 63;
    int beg = off[node], end = off[node + 1];
    const unsigned int* hb = (const unsigned int*)h1b;
    float s0x = 0.f, s0y = 0.f, s1x = 0.f, s1y = 0.f;
    float s2x = 0.f, s2y = 0.f, s3x = 0.f, s3y = 0.f;
    int s = beg;
    for (; s + 4 <= end; s += 4) {
        int r0 = csr_row[s], r1 = csr_row[s + 1], r2 = csr_row[s + 2], r3 = csr_row[s + 3];
        float a0 = a[r0], a1 = a[r1], a2 = a[r2], a3 = a[r3];
        unsigned int u0 = hb[(size_t)r0 * 64 + lane];
        unsigned int u1 = hb[(size_t)r1 * 64 + lane];
        unsigned int u2 = hb[(size_t)r2 * 64 + lane];
        unsigned int u3 = hb[(size_t)r3 * 64 + lane];
        s0x = fmaf(a0, blo(u0), s0x); s0y = fmaf(a0, bhi(u0), s0y);
        s1x = fmaf(a1, blo(u1), s1x); s1y = fmaf(a1, bhi(u1), s1y);
        s2x = fmaf(a2, blo(u2), s2x); s2y = fmaf(a2, bhi(u2), s2y);
        s3x = fmaf(a3, blo(u3), s3x); s3y = fmaf(a3, bhi(u3), s3y);
    }
    for (; s < end; ++s) {
        int r0 = csr_row[s];
        float a0 = a[r0];
        unsigned int u0 = hb[(size_t)r0 * 64 + lane];
        s0x = fmaf(a0, blo(u0), s0x); s0y = fmaf(a0, bhi(u0), s0y);
    }
    float dv = dinv[node];
    unsigned int ur = hb[(size_t)node * 64 + lane];
    float ox = fmaxf(fmaf(dv, s0x + s1x + s2x + s3x, blo(ur)), 0.0f);
    float oy = fmaxf(fmaf(dv, s0y + s1y + s2y + s3y, bhi(ur)), 0.0f);
    if constexpr (BF16OUT) {
        unsigned int pk = (unsigned int)f2b(ox) | ((unsigned int)f2b(oy) << 16);
        ((unsigned int*)out_v)[(size_t)node * 64 + lane] = pk;
    } else {
        ((float2*)out_v)[(size_t)node * 64 + lane] = make_float2(ox, oy);
    }
}

extern "C" void kernel_launch(void* const* d_in, const int* in_sizes, int n_in,
                              void* d_out, int out_size, void* d_ws, size_t ws_size,
                              hipStream_t stream) {
    const float* x    = (const float*)d_in[0];
    const int*   edge = (const int*)d_in[1];
    const float* Wt   = (const float*)d_in[2];
    const float* bt   = (const float*)d_in[3];
    const float* Wg   = (const float*)d_in[4];
    const float* bg   = (const float*)d_in[5];
    float* out = (float*)d_out;

    const int n = in_sizes[0] / DIM;      // 50000
    const int E = in_sizes[1] / 2;        // 600000
    const int* row = edge;
    const int* col = edge + E;

    int bshift = 6;
    while (((n + (1 << bshift) - 1) >> bshift) > 1024) ++bshift;
    const int nbuk = (n + (1 << bshift) - 1) >> bshift;
    const int nr = (n + RSIZE - 1) >> RBITS;
    const int ndeg = nr * NB2;

    // ---- byte-carved workspace ----
    char* base = (char*)d_ws;
    size_t o = 0;
    auto carve = [&](size_t bytes) -> void* {
        void* p = base + o;
        o += (bytes + 255) & ~(size_t)255;
        return p;
    };
    unsigned short* h1b  = (unsigned short*)carve((size_t)n * DIM * 2);
    unsigned short* hbuf = (unsigned short*)carve((size_t)n * DIM * 2);
    float* dinv          = (float*)carve((size_t)n * 4);
    float* a             = (float*)carve((size_t)n * 4);
    int*   off           = (int*)carve((size_t)(n + 1) * 4);
    int*   csr           = (int*)carve((size_t)E * 4);
    unsigned int* tmp    = (unsigned int*)carve((size_t)E * 4);
    int*   counts        = (int*)carve((size_t)NB1 * nbuk * 4);
    int*   bstart        = (int*)carve((size_t)(nbuk + 1) * 4);
    int*   tot           = (int*)carve((size_t)nbuk * 4);
    int*   gcounts       = (int*)carve((size_t)ndeg * RSIZE * 4);

    // ---- preprocessing: 4 kernels, no global atomics ----
    hists_kernel<<<ndeg + NB1, 256, 0, stream>>>(row, col, gcounts, counts,
                                                 E, ndeg, nbuk, bshift);
    const int nscan = (nbuk + 3) / 4;
    const int ndinv = (n + 255) / 256;
    scan_dinv_kernel<<<nscan + ndinv, 256, 0, stream>>>(counts, tot, gcounts, dinv,
                                                        nbuk, n, nscan);
    scatter_kernel<<<NB1, 256, 0, stream>>>(row, col, counts, tot, tmp, bstart,
                                            E, nbuk, bshift);
    bucket_group_kernel<<<nbuk, 256, 0, stream>>>(tmp, bstart, off, csr, n, E, bshift);

    // ---- two FA layers (bf16 inter-layer handoff) ----
    const int gt = (n + BM - 1) / BM;
    const int ga = (n + 3) / 4;

    transform_kernel<false><<<gt, 256, 0, stream>>>(
        x, Wt, bt, Wg, bg, dinv, h1b, a, n);
    agg_kernel<true><<<ga, 256, 0, stream>>>(off, csr, a, dinv, h1b, hbuf, n);

    transform_kernel<true><<<gt, 256, 0, stream>>>(
        hbuf, Wt + DIM * DIM, bt + DIM, Wg + DIM, bg + 1, dinv, h1b, a, n);
    agg_kernel<false><<<ga, 256, 0, stream>>>(off, csr, a, dinv, h1b, out, n);
}